// Round 2
// baseline (221.010 us; speedup 1.0000x reference)
//
#include <hip/hip_runtime.h>

// GaLiTe attention layer, MI355X/gfx950 — fp32 pipeline, f16x3-split MFMA proj
// (R19, 69->~26 us) + latency-optimized scan6 (R20). Shapes: T=64 B=16 DIM=512
// H=8 Dh=64 ETA=4 FD=256.
// d_out = fp32 [ output(64*16*512) | kv_last(16*8*256*64) | nm_last(16*8*256) ].
//
// R20: scan5 (58 us) was latency-bound: Occupancy 18.7% (512 blocks = 2
// waves/SIMD), VALUBusy 33%, HBM 6% — nothing saturated. scan6:
//  - 8 d-splits (grid 1024): 1 d-col per 32-lane half, 16 waves/CU. Costs 2x
//    redundant disc/gk/phiq L2 reads + nm/den compute (both far from limits).
//  - batched reduction: (n,den) partials for 8 t-steps held in regs (static
//    idx via unroll), ONE 5-stage butterfly per batch with 16-wide ILP,
//    instead of a serial 5-stage lgkmcnt chain per t. Same reduce order ->
//    bit-identical.
//
// Carried:
//  - proj mfma_f32_16x16x32_f16 Markidis hi+lo split (3 MFMA/frag): ~22
//    mantissa bits, rel err ~1e-6 (bf16's 2^-8 failed in R2/R3). acc fp32.
//  - gate precompute: ~10 us (transcendentals off the scan chain).
//  - out split-K=4 partials (dead-buffer aliased) + separate reduce: 15+3 us.

#define T_N   64
#define B_N   16
#define DIM_N 512
#define H_N   8
#define DH_N  64

#define OUT_ELEMS   524288   // T*B*DIM
#define KV_ELEMS    2097152  // B*H*FD*Dh
#define PROJ_ELEMS  2719744  // 5*524288 + 3*32768

typedef _Float16 f16;
typedef f16   f16x8 __attribute__((ext_vector_type(8)));
typedef float f32x4 __attribute__((ext_vector_type(4)));

__device__ __forceinline__ float sigmoidf_(float x) {
    return 1.0f / (1.0f + __expf(-x));
}

// ---------------------------------------------------------------------------
// gemm64_core (PROVEN, vector fp32): kept for out-GEMM.
// ---------------------------------------------------------------------------
__device__ __forceinline__ void gemm64_core(const float* __restrict__ A,
                                            const float* __restrict__ W,
                                            const float* __restrict__ bias,
                                            float* __restrict__ C, int N,
                                            int mb, int nb, int kBase, int kLen) {
    const int nbase = nb * 64;
    if (nbase >= N) return;

    __shared__ float As[2][16][68];
    __shared__ float Bs[2][16][68];

    const int tid = threadIdx.x;
    const int mbase = mb * 64;
    const int tx = tid & 15;
    const int ty = tid >> 4;
    const int sr = tid >> 2;
    const int sk = (tid & 3) << 2;
    const bool wok = (nbase + sr) < N;

    const float* Ap = A + (size_t)(mbase + sr) * 512 + kBase + sk;
    const float* Wp = W + (size_t)(nbase + sr) * 512 + kBase + sk;

    float4 av = *(const float4*)Ap;
    float4 wv = wok ? *(const float4*)Wp : make_float4(0.f, 0.f, 0.f, 0.f);
    As[0][sk + 0][sr] = av.x; As[0][sk + 1][sr] = av.y;
    As[0][sk + 2][sr] = av.z; As[0][sk + 3][sr] = av.w;
    Bs[0][sk + 0][sr] = wv.x; Bs[0][sk + 1][sr] = wv.y;
    Bs[0][sk + 2][sr] = wv.z; Bs[0][sk + 3][sr] = wv.w;

    float acc[4][4];
    #pragma unroll
    for (int i = 0; i < 4; ++i)
        #pragma unroll
        for (int j = 0; j < 4; ++j) acc[i][j] = 0.f;

    for (int k0 = 0; k0 < kLen; k0 += 16) {
        const int buf = (k0 >> 4) & 1;
        __syncthreads();
        const bool more = (k0 + 16) < kLen;
        if (more) {
            av = *(const float4*)(Ap + k0 + 16);
            wv = wok ? *(const float4*)(Wp + k0 + 16) : make_float4(0.f, 0.f, 0.f, 0.f);
        }
        #pragma unroll
        for (int k = 0; k < 16; ++k) {
            float4 a  = *(const float4*)&As[buf][k][ty << 2];
            float4 bq = *(const float4*)&Bs[buf][k][tx << 2];
            float ar[4] = {a.x, a.y, a.z, a.w};
            float br[4] = {bq.x, bq.y, bq.z, bq.w};
            #pragma unroll
            for (int i = 0; i < 4; ++i)
                #pragma unroll
                for (int j = 0; j < 4; ++j)
                    acc[i][j] = fmaf(ar[i], br[j], acc[i][j]);
        }
        if (more) {
            const int nbuf = buf ^ 1;
            As[nbuf][sk + 0][sr] = av.x; As[nbuf][sk + 1][sr] = av.y;
            As[nbuf][sk + 2][sr] = av.z; As[nbuf][sk + 3][sr] = av.w;
            Bs[nbuf][sk + 0][sr] = wv.x; Bs[nbuf][sk + 1][sr] = wv.y;
            Bs[nbuf][sk + 2][sr] = wv.z; Bs[nbuf][sk + 3][sr] = wv.w;
        }
    }

    #pragma unroll
    for (int i = 0; i < 4; ++i) {
        const int m = mbase + (ty << 2) + i;
        #pragma unroll
        for (int j = 0; j < 4; ++j) {
            const int n = nbase + (tx << 2) + j;
            if (n < N) {
                float v = acc[i][j];
                if (bias) v += bias[n];
                C[(size_t)m * N + n] = v;
            }
        }
    }
}

struct ProjW {
    const float* W[8];
    float*       D[8];
};

// ---------------------------------------------------------------------------
// proj_mfma_kernel (R19, PROVEN): 64x64 tile, 4 waves x 32x32 sub-tile via
// mfma_f32_16x16x32_f16 hi/lo split (3 MFMAs per fragment pair). Double-
// buffered LDS, stride 40 f16. Grid mapping z = id&7 -> XCD swizzle.
// ---------------------------------------------------------------------------
__device__ __forceinline__ void cvt_split_store(f16* __restrict__ dh,
                                                f16* __restrict__ dl,
                                                float4 v0, float4 v1) {
    float x[8] = {v0.x, v0.y, v0.z, v0.w, v1.x, v1.y, v1.z, v1.w};
    f16x8 h, lo;
    #pragma unroll
    for (int e = 0; e < 8; ++e) {
        f16 hh = (f16)x[e];
        h[e]  = hh;
        lo[e] = (f16)(x[e] - (float)hh);
    }
    *(f16x8*)dh = h;
    *(f16x8*)dl = lo;
}

__global__ __launch_bounds__(256) void proj_mfma_kernel(const float* __restrict__ X,
                                                        ProjW a) {
    const int id = blockIdx.x;
    const int z = id & 7;
    const int rem = id >> 3;
    const int mb = rem & 15;
    const int nb = rem >> 4;
    const int N = (z < 5) ? 512 : 32;
    const int nbase = nb * 64;
    if (nbase >= N) return;

    const float* __restrict__ W = a.W[z];
    float* __restrict__ C = a.D[z];
    const int mbase = mb * 64;

    __shared__ f16 AsH[2][64][40];
    __shared__ f16 AsL[2][64][40];
    __shared__ f16 BsH[2][64][40];
    __shared__ f16 BsL[2][64][40];

    const int tid = threadIdx.x;
    const int sr = tid >> 2;
    const int kq = (tid & 3) << 3;
    const bool wok = (nbase + sr) < N;
    const float* Ap = X + (size_t)(mbase + sr) * 512 + kq;
    const float* Wp = W + (size_t)(nbase + sr) * 512 + kq;

    const int l  = tid & 63;
    const int w  = tid >> 6;
    const int wr = (w >> 1) << 5;
    const int wc = (w & 1) << 5;
    const int lr = l & 15;
    const int lk = (l >> 4) << 3;

    f32x4 acc[2][2] = {};

    float4 xa0 = *(const float4*)(Ap);
    float4 xa1 = *(const float4*)(Ap + 4);
    float4 wb0 = wok ? *(const float4*)(Wp)     : make_float4(0.f, 0.f, 0.f, 0.f);
    float4 wb1 = wok ? *(const float4*)(Wp + 4) : make_float4(0.f, 0.f, 0.f, 0.f);
    cvt_split_store(&AsH[0][sr][kq], &AsL[0][sr][kq], xa0, xa1);
    cvt_split_store(&BsH[0][sr][kq], &BsL[0][sr][kq], wb0, wb1);

    for (int k0 = 0; k0 < 512; k0 += 32) {
        const int buf = (k0 >> 5) & 1;
        __syncthreads();
        const bool more = (k0 + 32) < 512;
        if (more) {
            xa0 = *(const float4*)(Ap + k0 + 32);
            xa1 = *(const float4*)(Ap + k0 + 36);
            wb0 = wok ? *(const float4*)(Wp + k0 + 32) : make_float4(0.f, 0.f, 0.f, 0.f);
            wb1 = wok ? *(const float4*)(Wp + k0 + 36) : make_float4(0.f, 0.f, 0.f, 0.f);
        }

        f16x8 aH[2], aL[2], bH[2], bL[2];
        #pragma unroll
        for (int i = 0; i < 2; ++i) {
            const int row = wr + i * 16 + lr;
            aH[i] = *(const f16x8*)&AsH[buf][row][lk];
            aL[i] = *(const f16x8*)&AsL[buf][row][lk];
        }
        #pragma unroll
        for (int j = 0; j < 2; ++j) {
            const int col = wc + j * 16 + lr;
            bH[j] = *(const f16x8*)&BsH[buf][col][lk];
            bL[j] = *(const f16x8*)&BsL[buf][col][lk];
        }

        #pragma unroll
        for (int i = 0; i < 2; ++i)
            #pragma unroll
            for (int j = 0; j < 2; ++j) {
                acc[i][j] = __builtin_amdgcn_mfma_f32_16x16x32_f16(aH[i], bH[j], acc[i][j], 0, 0, 0);
                acc[i][j] = __builtin_amdgcn_mfma_f32_16x16x32_f16(aH[i], bL[j], acc[i][j], 0, 0, 0);
                acc[i][j] = __builtin_amdgcn_mfma_f32_16x16x32_f16(aL[i], bH[j], acc[i][j], 0, 0, 0);
            }

        if (more) {
            const int nbuf = buf ^ 1;
            cvt_split_store(&AsH[nbuf][sr][kq], &AsL[nbuf][sr][kq], xa0, xa1);
            cvt_split_store(&BsH[nbuf][sr][kq], &BsL[nbuf][sr][kq], wb0, wb1);
        }
    }

    // C/D layout (m89/m91): col = lane&15, row = (lane>>4)*4 + reg
    #pragma unroll
    for (int j = 0; j < 2; ++j) {
        const int n = nbase + wc + j * 16 + lr;
        if (n < N) {
            #pragma unroll
            for (int i = 0; i < 2; ++i) {
                #pragma unroll
                for (int q = 0; q < 4; ++q) {
                    const int m = mbase + wr + i * 16 + ((l >> 4) << 2) + q;
                    C[(size_t)m * N + n] = acc[i][j][q];
                }
            }
        }
    }
}

// Fallback out GEMM (full K) — tiny-ws path only.
__global__ __launch_bounds__(256) void out_gemm_kernel(const float* __restrict__ A,
                                                       const float* __restrict__ W,
                                                       const float* __restrict__ bias,
                                                       float* __restrict__ C) {
    gemm64_core(A, W, bias, C, 512, blockIdx.x, blockIdx.y, 0, 512);
}

// out GEMM split-K=4 partials: grid 512, id = m + 16*(n + 8*kq); XCD = m%8.
struct OutP { float* P[4]; };
__global__ __launch_bounds__(256) void out_partial_kernel(const float* __restrict__ A,
                                                          const float* __restrict__ W,
                                                          OutP p) {
    const int id = blockIdx.x;
    const int m = id & 15;
    const int n = (id >> 4) & 7;
    const int kq = id >> 7;
    gemm64_core(A, W, nullptr, p.P[kq], 512, m, n, kq * 128, 128);
}

// reduce: out = P0+P1+P2+P3 + bias (fixed order -> deterministic). 131072 f4.
__global__ __launch_bounds__(256) void out_reduce_kernel(
    const float* __restrict__ p0, const float* __restrict__ p1,
    const float* __restrict__ p2, const float* __restrict__ p3,
    const float* __restrict__ bias, float* __restrict__ out) {
    const int i = blockIdx.x * 256 + threadIdx.x;     // float4 index
    float4 a = ((const float4*)p0)[i];
    float4 b = ((const float4*)p1)[i];
    float4 c = ((const float4*)p2)[i];
    float4 d = ((const float4*)p3)[i];
    float4 bv = ((const float4*)bias)[i & 127];
    float4 r;
    r.x = a.x + b.x + c.x + d.x + bv.x;
    r.y = a.y + b.y + c.y + d.y + bv.y;
    r.z = a.z + b.z + c.z + d.z + bv.z;
    r.w = a.w + b.w + c.w + d.w + bv.w;
    ((float4*)out)[i] = r;
}

// ---------------------------------------------------------------------------
// gate_kernel: precompute disc/gk/phiq per (t,b,h,D) and gv per (t,b,h,d).
// grid (8 h, 1024 rows) -> wg id % 8 = h (writer XCD = scan reader XCD).
// ---------------------------------------------------------------------------
__global__ __launch_bounds__(256) void gate_kernel(
    const float* __restrict__ qb,  const float* __restrict__ kb,
    const float* __restrict__ vb,  const float* __restrict__ bb,
    const float* __restrict__ gb,  const float* __restrict__ p1b,
    const float* __restrict__ p2b, const float* __restrict__ p3b,
    const int* __restrict__ term,
    float* __restrict__ disc_g, float* __restrict__ gk_g,
    float* __restrict__ phiq_g, float* __restrict__ gv_g) {
    const int h = blockIdx.x;
    const int row = blockIdx.y;        // t*16 + b
    const int D = threadIdx.x;
    const int e = D >> 6, di = D & 63;
    const size_t base = (size_t)row * 512 + h * 64;
    const size_t pb = (size_t)row * 32 + h * 4;

    float q = qb[base + di], k = kb[base + di], g = gb[base + di];
    float p1 = p1b[pb + e], p2 = p2b[pb + e], p3 = p3b[pb + e];
    float mask = 1.0f - (float)term[row];
    float gf = sigmoidf_(p3) * sigmoidf_(g);

    const size_t o = ((size_t)row * 8 + h) * 256 + D;
    disc_g[o] = (1.0f - gf) * mask;
    gk_g[o]   = fmaxf(p1, 0.f) * k * gf;
    phiq_g[o] = fmaxf(p2, 0.f) * q;
    if (D < 64)
        gv_g[((size_t)row * 8 + h) * 64 + D] = vb[base + D] * sigmoidf_(bb[base + D]);
}

// ---------------------------------------------------------------------------
// scan6 (R20): d-split x8. Grid 1024: blk = s*128 + bh (XCD = bh%8 = h).
// Block 256 thr = 4 waves; wave = 2 INDEPENDENT 32-lane halves.
// Half (l>>5) owns d-col s*8 + w*2 + half (1 col). Lane li = l&31 owns
// D = 8*li..8*li+8 (each half spans all 256 D).
// Reduction is BATCHED: (n,den) per-lane partials for 8 t-steps kept in regs
// (statically indexed — unrolled inner loop), then one 5-stage butterfly of
// 16 independent shuffles per batch. Same per-t reduce order as scan5 ->
// bit-identical output. attn overwrites vb (scan never reads vb).
// ---------------------------------------------------------------------------
__global__ __launch_bounds__(256) void scan6_kernel(
    const float* __restrict__ disc_g, const float* __restrict__ gk_g,
    const float* __restrict__ phiq_g, const float* __restrict__ gv_g,
    float* __restrict__ vb /* attn out */,
    const float* __restrict__ kv0, const float* __restrict__ nm0,
    float* __restrict__ dout) {
    const int blk = blockIdx.x;       // 1024 = 8 splits x 128 bh
    const int bh = blk & 127;
    const int s  = blk >> 7;          // 0..7
    const int b  = bh >> 3;
    const int h  = bh & 7;
    const int tid = threadIdx.x;
    const int w = tid >> 6;
    const int l = tid & 63;
    const int half = l >> 5;
    const int li = l & 31;
    const int d0 = s * 8 + w * 2 + half;        // lane's single d-col
    const int D0 = li << 3;                     // lane's 8 D

    float kv[8];
    float nm[8];
    {
        const float* kp = kv0 + ((size_t)bh * 256 + D0) * 64 + d0;
        #pragma unroll
        for (int j = 0; j < 8; ++j) kv[j] = kp[(size_t)j * 64];
        float4 na  = *(const float4*)(nm0 + (size_t)bh * 256 + D0);
        float4 nb_ = *(const float4*)(nm0 + (size_t)bh * 256 + D0 + 4);
        nm[0] = na.x; nm[1] = na.y; nm[2] = na.z; nm[3] = na.w;
        nm[4] = nb_.x; nm[5] = nb_.y; nm[6] = nb_.z; nm[7] = nb_.w;
    }

    float4 cd0, cd1, cg0, cg1, cp0, cp1; float cgv;
    {
        const size_t go = ((size_t)b * 8 + h) * 256 + D0;
        cd0 = *(const float4*)(disc_g + go);  cd1 = *(const float4*)(disc_g + go + 4);
        cg0 = *(const float4*)(gk_g + go);    cg1 = *(const float4*)(gk_g + go + 4);
        cp0 = *(const float4*)(phiq_g + go);  cp1 = *(const float4*)(phiq_g + go + 4);
        cgv = gv_g[((size_t)b * 8 + h) * 64 + d0];
    }

    float nP[8], dP[8];

    for (int tb = 0; tb < 8; ++tb) {
        #pragma unroll
        for (int tt = 0; tt < 8; ++tt) {
            const int t = tb * 8 + tt;
            const int row = t * B_N + b;

            float4 nd0 = {}, nd1 = {}, ng0 = {}, ng1 = {}, np0 = {}, np1 = {};
            float ngv = 0.f;
            if (t + 1 < T_N) {
                const size_t go2 = ((size_t)(row + B_N) * 8 + h) * 256 + D0;
                nd0 = *(const float4*)(disc_g + go2); nd1 = *(const float4*)(disc_g + go2 + 4);
                ng0 = *(const float4*)(gk_g + go2);   ng1 = *(const float4*)(gk_g + go2 + 4);
                np0 = *(const float4*)(phiq_g + go2); np1 = *(const float4*)(phiq_g + go2 + 4);
                ngv = gv_g[((size_t)(row + B_N) * 8 + h) * 64 + d0];
            }

            const float dj[8]  = {cd0.x, cd0.y, cd0.z, cd0.w, cd1.x, cd1.y, cd1.z, cd1.w};
            const float gkj[8] = {cg0.x, cg0.y, cg0.z, cg0.w, cg1.x, cg1.y, cg1.z, cg1.w};
            const float phj[8] = {cp0.x, cp0.y, cp0.z, cp0.w, cp1.x, cp1.y, cp1.z, cp1.w};

            float den = 0.f, n0 = 0.f;
            #pragma unroll
            for (int j = 0; j < 8; ++j) {
                nm[j] = dj[j] * nm[j] + gkj[j];
                den = fmaf(phj[j], nm[j], den);
                kv[j] = dj[j] * kv[j] + gkj[j] * cgv;
                n0 = fmaf(phj[j], kv[j], n0);
            }
            nP[tt] = n0; dP[tt] = den;

            cd0 = nd0; cd1 = nd1; cg0 = ng0; cg1 = ng1; cp0 = np0; cp1 = np1; cgv = ngv;
        }

        // batched butterfly: 5 stages x 16 independent shuffles (xor stays
        // within the 32-lane half for ofs <= 16).
        #pragma unroll
        for (int ofs = 1; ofs <= 16; ofs <<= 1) {
            #pragma unroll
            for (int tt = 0; tt < 8; ++tt) {
                nP[tt] += __shfl_xor(nP[tt], ofs);
                dP[tt] += __shfl_xor(dP[tt], ofs);
            }
        }

        if (li == 0) {
            #pragma unroll
            for (int tt = 0; tt < 8; ++tt) {
                const int row = (tb * 8 + tt) * B_N + b;
                vb[(size_t)row * 512 + h * 64 + d0] = nP[tt] / (dP[tt] + 1e-6f);
            }
        }
    }

    {
        float* kp = dout + OUT_ELEMS + ((size_t)bh * 256 + D0) * 64 + d0;
        #pragma unroll
        for (int j = 0; j < 8; ++j) kp[(size_t)j * 64] = kv[j];
        if (s == 0 && w == 0 && half == 0) {
            float* np = dout + OUT_ELEMS + KV_ELEMS + (size_t)bh * 256 + D0;
            *(float4*)np       = make_float4(nm[0], nm[1], nm[2], nm[3]);
            *(float4*)(np + 4) = make_float4(nm[4], nm[5], nm[6], nm[7]);
        }
    }
}

// ---------------------------------------------------------------------------
extern "C" void kernel_launch(void* const* d_in, const int* in_sizes, int n_in,
                              void* d_out, int out_size, void* d_ws, size_t ws_size,
                              hipStream_t stream) {
    (void)in_sizes; (void)n_in; (void)out_size;

    const float* X    = (const float*)d_in[0];
    const int*   term = (const int*)  d_in[1];
    const float* kv0  = (const float*)d_in[2];
    const float* nm0  = (const float*)d_in[3];
    const float* Wo   = (const float*)d_in[12];
    const float* bo   = (const float*)d_in[13];

    float* out = (float*)d_out;

    // ---- workspace (38.1 MB total — PROVEN available since R9) ----
    float* qb  = (float*)d_ws;            // proj outputs; qb/kb/bb/gb reused
    float* kb  = qb  + 524288;            // as out-GEMM partials after gate
    float* vb  = kb  + 524288;            // v, later attn
    float* bb  = vb  + 524288;
    float* gb  = bb  + 524288;
    float* p1b = gb  + 524288;
    float* p2b = p1b + 32768;
    float* p3b = p2b + 32768;
    float* disc_g = p3b + 32768;          // 26 MB gating region
    float* gk_g   = disc_g + 2097152;
    float* phiq_g = gk_g   + 2097152;
    float* gv_g   = phiq_g + 2097152;
    const size_t need_bytes = (size_t)(PROJ_ELEMS + 6815744) * 4;  // 38.1 MB
    const bool big = ws_size >= need_bytes;

    ProjW pa;
    pa.W[0] = (const float*)d_in[4];  pa.W[1] = (const float*)d_in[5];
    pa.W[2] = (const float*)d_in[6];  pa.W[3] = (const float*)d_in[7];
    pa.W[4] = (const float*)d_in[8];  pa.W[5] = (const float*)d_in[9];
    pa.W[6] = (const float*)d_in[10]; pa.W[7] = (const float*)d_in[11];
    pa.D[0] = qb;  pa.D[1] = kb;  pa.D[2] = vb;  pa.D[3] = bb;
    pa.D[4] = gb;  pa.D[5] = p1b; pa.D[6] = p2b; pa.D[7] = p3b;
    proj_mfma_kernel<<<1024, 256, 0, stream>>>(X, pa);

    gate_kernel<<<dim3(8, 1024), 256, 0, stream>>>(qb, kb, vb, bb, gb,
                                                   p1b, p2b, p3b, term,
                                                   disc_g, gk_g, phiq_g, gv_g);
    scan6_kernel<<<1024, 256, 0, stream>>>(disc_g, gk_g, phiq_g, gv_g,
                                           vb, kv0, nm0, out);
    if (big) {
        // out = attn @ Wo^T + bo, split-K=4 into the dead q/k/b/g buffers
        OutP op; op.P[0] = qb; op.P[1] = kb; op.P[2] = bb; op.P[3] = gb;
        out_partial_kernel<<<512, 256, 0, stream>>>(vb, Wo, op);
        out_reduce_kernel<<<512, 256, 0, stream>>>(qb, kb, bb, gb, bo, out);
    } else {
        out_gemm_kernel<<<dim3(16, 8), 256, 0, stream>>>(vb, Wo, bo, out);
    }
}

// Round 3
// 190.937 us; speedup vs baseline: 1.1575x; 1.1575x over previous
//
#include <hip/hip_runtime.h>

// GaLiTe attention layer, MI355X/gfx950 — fp32 pipeline, f16x3-split MFMA proj
// (R19, 69->~26 us) + depth-2-prefetch scan7 (R21). Shapes: T=64 B=16 DIM=512
// H=8 Dh=64 ETA=4 FD=256.
// d_out = fp32 [ output(64*16*512) | kv_last(16*8*256*64) | nm_last(16*8*256) ].
//
// R21: scan6 (R20) REVERTED — batching 8 steps let the compiler pipeline all
// 8 loads into registers (VGPR 48->156), occupancy fell 18.7->10%, fetch 2x:
// 101 us vs scan5's 58. Both scans stream at ~500 GB/s effective = latency-
// bound (Little's law), grid-limited at 2 blocks/CU with huge VGPR headroom.
// scan7 = scan5 exact structure + explicit depth-2 prefetch via two NAMED
// buffer sets (static indexing, no arrays -> no scratch): capture buf ->
// issue load for t+2 -> compute. 2x bytes-in-flight/wave, same reduce order
// (bit-identical), VGPR ~100 (2 waves/SIMD x 100 << 512: still 2 blocks/CU).
//
// Carried:
//  - proj mfma_f32_16x16x32_f16 Markidis hi+lo split (3 MFMA/frag): ~22
//    mantissa bits, rel err ~1e-6 (bf16's 2^-8 failed in R2/R3). acc fp32.
//  - gate precompute: ~10 us (transcendentals off the scan chain).
//  - scan5 layout: 4 d-splits, 32-lane halves, 5x3 butterflies.
//  - out split-K=4 partials (dead-buffer aliased) + separate reduce: 15+3 us.

#define T_N   64
#define B_N   16
#define DIM_N 512
#define H_N   8
#define DH_N  64

#define OUT_ELEMS   524288   // T*B*DIM
#define KV_ELEMS    2097152  // B*H*FD*Dh
#define PROJ_ELEMS  2719744  // 5*524288 + 3*32768

typedef _Float16 f16;
typedef f16   f16x8 __attribute__((ext_vector_type(8)));
typedef float f32x4 __attribute__((ext_vector_type(4)));

__device__ __forceinline__ float sigmoidf_(float x) {
    return 1.0f / (1.0f + __expf(-x));
}

// ---------------------------------------------------------------------------
// gemm64_core (PROVEN, vector fp32): kept for out-GEMM.
// ---------------------------------------------------------------------------
__device__ __forceinline__ void gemm64_core(const float* __restrict__ A,
                                            const float* __restrict__ W,
                                            const float* __restrict__ bias,
                                            float* __restrict__ C, int N,
                                            int mb, int nb, int kBase, int kLen) {
    const int nbase = nb * 64;
    if (nbase >= N) return;

    __shared__ float As[2][16][68];
    __shared__ float Bs[2][16][68];

    const int tid = threadIdx.x;
    const int mbase = mb * 64;
    const int tx = tid & 15;
    const int ty = tid >> 4;
    const int sr = tid >> 2;
    const int sk = (tid & 3) << 2;
    const bool wok = (nbase + sr) < N;

    const float* Ap = A + (size_t)(mbase + sr) * 512 + kBase + sk;
    const float* Wp = W + (size_t)(nbase + sr) * 512 + kBase + sk;

    float4 av = *(const float4*)Ap;
    float4 wv = wok ? *(const float4*)Wp : make_float4(0.f, 0.f, 0.f, 0.f);
    As[0][sk + 0][sr] = av.x; As[0][sk + 1][sr] = av.y;
    As[0][sk + 2][sr] = av.z; As[0][sk + 3][sr] = av.w;
    Bs[0][sk + 0][sr] = wv.x; Bs[0][sk + 1][sr] = wv.y;
    Bs[0][sk + 2][sr] = wv.z; Bs[0][sk + 3][sr] = wv.w;

    float acc[4][4];
    #pragma unroll
    for (int i = 0; i < 4; ++i)
        #pragma unroll
        for (int j = 0; j < 4; ++j) acc[i][j] = 0.f;

    for (int k0 = 0; k0 < kLen; k0 += 16) {
        const int buf = (k0 >> 4) & 1;
        __syncthreads();
        const bool more = (k0 + 16) < kLen;
        if (more) {
            av = *(const float4*)(Ap + k0 + 16);
            wv = wok ? *(const float4*)(Wp + k0 + 16) : make_float4(0.f, 0.f, 0.f, 0.f);
        }
        #pragma unroll
        for (int k = 0; k < 16; ++k) {
            float4 a  = *(const float4*)&As[buf][k][ty << 2];
            float4 bq = *(const float4*)&Bs[buf][k][tx << 2];
            float ar[4] = {a.x, a.y, a.z, a.w};
            float br[4] = {bq.x, bq.y, bq.z, bq.w};
            #pragma unroll
            for (int i = 0; i < 4; ++i)
                #pragma unroll
                for (int j = 0; j < 4; ++j)
                    acc[i][j] = fmaf(ar[i], br[j], acc[i][j]);
        }
        if (more) {
            const int nbuf = buf ^ 1;
            As[nbuf][sk + 0][sr] = av.x; As[nbuf][sk + 1][sr] = av.y;
            As[nbuf][sk + 2][sr] = av.z; As[nbuf][sk + 3][sr] = av.w;
            Bs[nbuf][sk + 0][sr] = wv.x; Bs[nbuf][sk + 1][sr] = wv.y;
            Bs[nbuf][sk + 2][sr] = wv.z; Bs[nbuf][sk + 3][sr] = wv.w;
        }
    }

    #pragma unroll
    for (int i = 0; i < 4; ++i) {
        const int m = mbase + (ty << 2) + i;
        #pragma unroll
        for (int j = 0; j < 4; ++j) {
            const int n = nbase + (tx << 2) + j;
            if (n < N) {
                float v = acc[i][j];
                if (bias) v += bias[n];
                C[(size_t)m * N + n] = v;
            }
        }
    }
}

struct ProjW {
    const float* W[8];
    float*       D[8];
};

// ---------------------------------------------------------------------------
// proj_mfma_kernel (R19, PROVEN): 64x64 tile, 4 waves x 32x32 sub-tile via
// mfma_f32_16x16x32_f16 hi/lo split (3 MFMAs per fragment pair). Double-
// buffered LDS, stride 40 f16. Grid mapping z = id&7 -> XCD swizzle.
// ---------------------------------------------------------------------------
__device__ __forceinline__ void cvt_split_store(f16* __restrict__ dh,
                                                f16* __restrict__ dl,
                                                float4 v0, float4 v1) {
    float x[8] = {v0.x, v0.y, v0.z, v0.w, v1.x, v1.y, v1.z, v1.w};
    f16x8 h, lo;
    #pragma unroll
    for (int e = 0; e < 8; ++e) {
        f16 hh = (f16)x[e];
        h[e]  = hh;
        lo[e] = (f16)(x[e] - (float)hh);
    }
    *(f16x8*)dh = h;
    *(f16x8*)dl = lo;
}

__global__ __launch_bounds__(256) void proj_mfma_kernel(const float* __restrict__ X,
                                                        ProjW a) {
    const int id = blockIdx.x;
    const int z = id & 7;
    const int rem = id >> 3;
    const int mb = rem & 15;
    const int nb = rem >> 4;
    const int N = (z < 5) ? 512 : 32;
    const int nbase = nb * 64;
    if (nbase >= N) return;

    const float* __restrict__ W = a.W[z];
    float* __restrict__ C = a.D[z];
    const int mbase = mb * 64;

    __shared__ f16 AsH[2][64][40];
    __shared__ f16 AsL[2][64][40];
    __shared__ f16 BsH[2][64][40];
    __shared__ f16 BsL[2][64][40];

    const int tid = threadIdx.x;
    const int sr = tid >> 2;
    const int kq = (tid & 3) << 3;
    const bool wok = (nbase + sr) < N;
    const float* Ap = X + (size_t)(mbase + sr) * 512 + kq;
    const float* Wp = W + (size_t)(nbase + sr) * 512 + kq;

    const int l  = tid & 63;
    const int w  = tid >> 6;
    const int wr = (w >> 1) << 5;
    const int wc = (w & 1) << 5;
    const int lr = l & 15;
    const int lk = (l >> 4) << 3;

    f32x4 acc[2][2] = {};

    float4 xa0 = *(const float4*)(Ap);
    float4 xa1 = *(const float4*)(Ap + 4);
    float4 wb0 = wok ? *(const float4*)(Wp)     : make_float4(0.f, 0.f, 0.f, 0.f);
    float4 wb1 = wok ? *(const float4*)(Wp + 4) : make_float4(0.f, 0.f, 0.f, 0.f);
    cvt_split_store(&AsH[0][sr][kq], &AsL[0][sr][kq], xa0, xa1);
    cvt_split_store(&BsH[0][sr][kq], &BsL[0][sr][kq], wb0, wb1);

    for (int k0 = 0; k0 < 512; k0 += 32) {
        const int buf = (k0 >> 5) & 1;
        __syncthreads();
        const bool more = (k0 + 32) < 512;
        if (more) {
            xa0 = *(const float4*)(Ap + k0 + 32);
            xa1 = *(const float4*)(Ap + k0 + 36);
            wb0 = wok ? *(const float4*)(Wp + k0 + 32) : make_float4(0.f, 0.f, 0.f, 0.f);
            wb1 = wok ? *(const float4*)(Wp + k0 + 36) : make_float4(0.f, 0.f, 0.f, 0.f);
        }

        f16x8 aH[2], aL[2], bH[2], bL[2];
        #pragma unroll
        for (int i = 0; i < 2; ++i) {
            const int row = wr + i * 16 + lr;
            aH[i] = *(const f16x8*)&AsH[buf][row][lk];
            aL[i] = *(const f16x8*)&AsL[buf][row][lk];
        }
        #pragma unroll
        for (int j = 0; j < 2; ++j) {
            const int col = wc + j * 16 + lr;
            bH[j] = *(const f16x8*)&BsH[buf][col][lk];
            bL[j] = *(const f16x8*)&BsL[buf][col][lk];
        }

        #pragma unroll
        for (int i = 0; i < 2; ++i)
            #pragma unroll
            for (int j = 0; j < 2; ++j) {
                acc[i][j] = __builtin_amdgcn_mfma_f32_16x16x32_f16(aH[i], bH[j], acc[i][j], 0, 0, 0);
                acc[i][j] = __builtin_amdgcn_mfma_f32_16x16x32_f16(aH[i], bL[j], acc[i][j], 0, 0, 0);
                acc[i][j] = __builtin_amdgcn_mfma_f32_16x16x32_f16(aL[i], bH[j], acc[i][j], 0, 0, 0);
            }

        if (more) {
            const int nbuf = buf ^ 1;
            cvt_split_store(&AsH[nbuf][sr][kq], &AsL[nbuf][sr][kq], xa0, xa1);
            cvt_split_store(&BsH[nbuf][sr][kq], &BsL[nbuf][sr][kq], wb0, wb1);
        }
    }

    // C/D layout (m89/m91): col = lane&15, row = (lane>>4)*4 + reg
    #pragma unroll
    for (int j = 0; j < 2; ++j) {
        const int n = nbase + wc + j * 16 + lr;
        if (n < N) {
            #pragma unroll
            for (int i = 0; i < 2; ++i) {
                #pragma unroll
                for (int q = 0; q < 4; ++q) {
                    const int m = mbase + wr + i * 16 + ((l >> 4) << 2) + q;
                    C[(size_t)m * N + n] = acc[i][j][q];
                }
            }
        }
    }
}

// Fallback out GEMM (full K) — tiny-ws path only.
__global__ __launch_bounds__(256) void out_gemm_kernel(const float* __restrict__ A,
                                                       const float* __restrict__ W,
                                                       const float* __restrict__ bias,
                                                       float* __restrict__ C) {
    gemm64_core(A, W, bias, C, 512, blockIdx.x, blockIdx.y, 0, 512);
}

// out GEMM split-K=4 partials: grid 512, id = m + 16*(n + 8*kq); XCD = m%8.
struct OutP { float* P[4]; };
__global__ __launch_bounds__(256) void out_partial_kernel(const float* __restrict__ A,
                                                          const float* __restrict__ W,
                                                          OutP p) {
    const int id = blockIdx.x;
    const int m = id & 15;
    const int n = (id >> 4) & 7;
    const int kq = id >> 7;
    gemm64_core(A, W, nullptr, p.P[kq], 512, m, n, kq * 128, 128);
}

// reduce: out = P0+P1+P2+P3 + bias (fixed order -> deterministic). 131072 f4.
__global__ __launch_bounds__(256) void out_reduce_kernel(
    const float* __restrict__ p0, const float* __restrict__ p1,
    const float* __restrict__ p2, const float* __restrict__ p3,
    const float* __restrict__ bias, float* __restrict__ out) {
    const int i = blockIdx.x * 256 + threadIdx.x;     // float4 index
    float4 a = ((const float4*)p0)[i];
    float4 b = ((const float4*)p1)[i];
    float4 c = ((const float4*)p2)[i];
    float4 d = ((const float4*)p3)[i];
    float4 bv = ((const float4*)bias)[i & 127];
    float4 r;
    r.x = a.x + b.x + c.x + d.x + bv.x;
    r.y = a.y + b.y + c.y + d.y + bv.y;
    r.z = a.z + b.z + c.z + d.z + bv.z;
    r.w = a.w + b.w + c.w + d.w + bv.w;
    ((float4*)out)[i] = r;
}

// ---------------------------------------------------------------------------
// gate_kernel: precompute disc/gk/phiq per (t,b,h,D) and gv per (t,b,h,d).
// grid (8 h, 1024 rows) -> wg id % 8 = h (writer XCD = scan reader XCD).
// ---------------------------------------------------------------------------
__global__ __launch_bounds__(256) void gate_kernel(
    const float* __restrict__ qb,  const float* __restrict__ kb,
    const float* __restrict__ vb,  const float* __restrict__ bb,
    const float* __restrict__ gb,  const float* __restrict__ p1b,
    const float* __restrict__ p2b, const float* __restrict__ p3b,
    const int* __restrict__ term,
    float* __restrict__ disc_g, float* __restrict__ gk_g,
    float* __restrict__ phiq_g, float* __restrict__ gv_g) {
    const int h = blockIdx.x;
    const int row = blockIdx.y;        // t*16 + b
    const int D = threadIdx.x;
    const int e = D >> 6, di = D & 63;
    const size_t base = (size_t)row * 512 + h * 64;
    const size_t pb = (size_t)row * 32 + h * 4;

    float q = qb[base + di], k = kb[base + di], g = gb[base + di];
    float p1 = p1b[pb + e], p2 = p2b[pb + e], p3 = p3b[pb + e];
    float mask = 1.0f - (float)term[row];
    float gf = sigmoidf_(p3) * sigmoidf_(g);

    const size_t o = ((size_t)row * 8 + h) * 256 + D;
    disc_g[o] = (1.0f - gf) * mask;
    gk_g[o]   = fmaxf(p1, 0.f) * k * gf;
    phiq_g[o] = fmaxf(p2, 0.f) * q;
    if (D < 64)
        gv_g[((size_t)row * 8 + h) * 64 + D] = vb[base + D] * sigmoidf_(bb[base + D]);
}

// ---------------------------------------------------------------------------
// scan7 (R21): scan5 structure + depth-2 prefetch. Grid 512: blk = s*128 + bh
// (XCD = bh%8 = h). Block 256 thr = 4 waves; wave = 2 INDEPENDENT 32-lane
// halves. Half (l>>5) owns cols s*16+w*4+2*half+{0,1}. Lane li = l&31 owns
// D = 8*li..8*li+8. Two NAMED buffer sets A/B: at step t, capture buf ->
// issue load t+2 into same named buf -> compute/butterfly/write. 2x bytes in
// flight; per-t reduce order identical to scan5 -> bit-identical output.
// attn overwrites vb (scan never reads vb; out_partial reads it after).
// ---------------------------------------------------------------------------
#define LOADG(P, tt) do { \
    const size_t go_ = (size_t)(tt) * 32768 + gbase; \
    P##d0 = *(const float4*)(disc_g + go_); P##d1 = *(const float4*)(disc_g + go_ + 4); \
    P##g0 = *(const float4*)(gk_g + go_);   P##g1 = *(const float4*)(gk_g + go_ + 4); \
    P##p0 = *(const float4*)(phiq_g + go_); P##p1 = *(const float4*)(phiq_g + go_ + 4); \
    P##gv = *(const float2*)(gv_g + (size_t)(tt) * 8192 + gvb); \
} while (0)

#define STEPC(P, tt) do { \
    const float dj[8]  = {P##d0.x, P##d0.y, P##d0.z, P##d0.w, P##d1.x, P##d1.y, P##d1.z, P##d1.w}; \
    const float gkj[8] = {P##g0.x, P##g0.y, P##g0.z, P##g0.w, P##g1.x, P##g1.y, P##g1.z, P##g1.w}; \
    const float phj[8] = {P##p0.x, P##p0.y, P##p0.z, P##p0.w, P##p1.x, P##p1.y, P##p1.z, P##p1.w}; \
    const float gvx = P##gv.x, gvy = P##gv.y; \
    if ((tt) + 2 < T_N) LOADG(P, (tt) + 2); \
    float den = 0.f, n0 = 0.f, n1 = 0.f; \
    _Pragma("unroll") \
    for (int j = 0; j < 8; ++j) { \
        nm[j] = dj[j] * nm[j] + gkj[j]; \
        den = fmaf(phj[j], nm[j], den); \
        kv[j][0] = dj[j] * kv[j][0] + gkj[j] * gvx; n0 = fmaf(phj[j], kv[j][0], n0); \
        kv[j][1] = dj[j] * kv[j][1] + gkj[j] * gvy; n1 = fmaf(phj[j], kv[j][1], n1); \
    } \
    _Pragma("unroll") \
    for (int ofs = 1; ofs <= 16; ofs <<= 1) { \
        n0 += __shfl_xor(n0, ofs); n1 += __shfl_xor(n1, ofs); den += __shfl_xor(den, ofs); \
    } \
    if (li == 0) { \
        const size_t vbo = (size_t)((tt) * B_N + b) * 512 + h * 64 + d0; \
        vb[vbo]     = n0 / (den + 1e-6f); \
        vb[vbo + 1] = n1 / (den + 1e-6f); \
    } \
} while (0)

__global__ __launch_bounds__(256) void scan7_kernel(
    const float* __restrict__ disc_g, const float* __restrict__ gk_g,
    const float* __restrict__ phiq_g, const float* __restrict__ gv_g,
    float* __restrict__ vb /* attn out */,
    const float* __restrict__ kv0, const float* __restrict__ nm0,
    float* __restrict__ dout) {
    const int blk = blockIdx.x;       // 512 = 4 splits x 128 bh
    const int bh = blk & 127;
    const int s  = blk >> 7;          // 0..3
    const int b  = bh >> 3;
    const int h  = bh & 7;
    const int tid = threadIdx.x;
    const int w = tid >> 6;
    const int l = tid & 63;
    const int half = l >> 5;
    const int li = l & 31;
    const int d0 = s * 16 + w * 4 + half * 2;   // lane's 2 d-cols
    const int D0 = li << 3;                     // lane's 8 D

    const size_t gbase = ((size_t)b * 8 + h) * 256 + D0;
    const size_t gvb   = ((size_t)b * 8 + h) * 64 + d0;

    float kv[8][2];
    float nm[8];
    {
        const float* kp = kv0 + ((size_t)bh * 256 + D0) * 64 + d0;
        #pragma unroll
        for (int j = 0; j < 8; ++j) {
            float2 r = *(const float2*)(kp + (size_t)j * 64);
            kv[j][0] = r.x; kv[j][1] = r.y;
        }
        float4 na  = *(const float4*)(nm0 + (size_t)bh * 256 + D0);
        float4 nb_ = *(const float4*)(nm0 + (size_t)bh * 256 + D0 + 4);
        nm[0] = na.x; nm[1] = na.y; nm[2] = na.z; nm[3] = na.w;
        nm[4] = nb_.x; nm[5] = nb_.y; nm[6] = nb_.z; nm[7] = nb_.w;
    }

    float4 Ad0, Ad1, Ag0, Ag1, Ap0, Ap1; float2 Agv;
    float4 Bd0, Bd1, Bg0, Bg1, Bp0, Bp1; float2 Bgv;
    LOADG(A, 0);
    LOADG(B, 1);

    for (int t = 0; t < T_N; t += 2) {
        STEPC(A, t);
        STEPC(B, t + 1);
    }

    {
        float* kp = dout + OUT_ELEMS + ((size_t)bh * 256 + D0) * 64 + d0;
        #pragma unroll
        for (int j = 0; j < 8; ++j)
            *(float2*)(kp + (size_t)j * 64) = make_float2(kv[j][0], kv[j][1]);
        if (s == 0 && w == 0 && half == 0) {
            float* np = dout + OUT_ELEMS + KV_ELEMS + (size_t)bh * 256 + D0;
            *(float4*)np       = make_float4(nm[0], nm[1], nm[2], nm[3]);
            *(float4*)(np + 4) = make_float4(nm[4], nm[5], nm[6], nm[7]);
        }
    }
}

// ---------------------------------------------------------------------------
extern "C" void kernel_launch(void* const* d_in, const int* in_sizes, int n_in,
                              void* d_out, int out_size, void* d_ws, size_t ws_size,
                              hipStream_t stream) {
    (void)in_sizes; (void)n_in; (void)out_size;

    const float* X    = (const float*)d_in[0];
    const int*   term = (const int*)  d_in[1];
    const float* kv0  = (const float*)d_in[2];
    const float* nm0  = (const float*)d_in[3];
    const float* Wo   = (const float*)d_in[12];
    const float* bo   = (const float*)d_in[13];

    float* out = (float*)d_out;

    // ---- workspace (38.1 MB total — PROVEN available since R9) ----
    float* qb  = (float*)d_ws;            // proj outputs; qb/kb/bb/gb reused
    float* kb  = qb  + 524288;            // as out-GEMM partials after gate
    float* vb  = kb  + 524288;            // v, later attn
    float* bb  = vb  + 524288;
    float* gb  = bb  + 524288;
    float* p1b = gb  + 524288;
    float* p2b = p1b + 32768;
    float* p3b = p2b + 32768;
    float* disc_g = p3b + 32768;          // 26 MB gating region
    float* gk_g   = disc_g + 2097152;
    float* phiq_g = gk_g   + 2097152;
    float* gv_g   = phiq_g + 2097152;
    const size_t need_bytes = (size_t)(PROJ_ELEMS + 6815744) * 4;  // 38.1 MB
    const bool big = ws_size >= need_bytes;

    ProjW pa;
    pa.W[0] = (const float*)d_in[4];  pa.W[1] = (const float*)d_in[5];
    pa.W[2] = (const float*)d_in[6];  pa.W[3] = (const float*)d_in[7];
    pa.W[4] = (const float*)d_in[8];  pa.W[5] = (const float*)d_in[9];
    pa.W[6] = (const float*)d_in[10]; pa.W[7] = (const float*)d_in[11];
    pa.D[0] = qb;  pa.D[1] = kb;  pa.D[2] = vb;  pa.D[3] = bb;
    pa.D[4] = gb;  pa.D[5] = p1b; pa.D[6] = p2b; pa.D[7] = p3b;
    proj_mfma_kernel<<<1024, 256, 0, stream>>>(X, pa);

    gate_kernel<<<dim3(8, 1024), 256, 0, stream>>>(qb, kb, vb, bb, gb,
                                                   p1b, p2b, p3b, term,
                                                   disc_g, gk_g, phiq_g, gv_g);
    scan7_kernel<<<512, 256, 0, stream>>>(disc_g, gk_g, phiq_g, gv_g,
                                          vb, kv0, nm0, out);
    if (big) {
        // out = attn @ Wo^T + bo, split-K=4 into the dead q/k/b/g buffers
        OutP op; op.P[0] = qb; op.P[1] = kb; op.P[2] = bb; op.P[3] = gb;
        out_partial_kernel<<<512, 256, 0, stream>>>(vb, Wo, op);
        out_reduce_kernel<<<512, 256, 0, stream>>>(qb, kb, bb, gb, bo, out);
    } else {
        out_gemm_kernel<<<dim3(16, 8), 256, 0, stream>>>(vb, Wo, bo, out);
    }
}

// Round 4
// 175.777 us; speedup vs baseline: 1.2573x; 1.0862x over previous
//
#include <hip/hip_runtime.h>

// GaLiTe attention layer, MI355X/gfx950 — fp32 pipeline, f16x3-split MFMA proj
// (R19, 69->~26 us) + DPP-reduce scan8 (R22). Shapes: T=64 B=16 DIM=512 H=8
// Dh=64 ETA=4 FD=256.
// d_out = fp32 [ output(64*16*512) | kv_last(16*8*256*64) | nm_last(16*8*256) ].
//
// R22: scan latency autopsy. R20 (8-way split + batched loads) -> VGPR 156,
// occupancy 10%, 101 us. R21 (depth-2 vmem prefetch) -> 67 us (worse than
// scan5's 58). Both falsify "vmem bytes-in-flight" as the limiter. Remaining
// serial term: the per-step 5-stage __shfl_xor butterfly = 5 DEPENDENT
// ds_swizzle_b32 (LDS pipe, ~120+ cyc each) = 600-1500 cyc of the observed
// ~2100 cyc/step. scan8 = scan5 EXACT structure with the butterfly moved to
// the VALU pipe via DPP: quad_perm xor1/xor2, row_half_mirror, row_mirror
// (valid: after stage k all lanes of a group hold the group sum), then
// row_bcast15 (row_mask 0xA) -> 32-lane half sums land in lanes 16-31/48-63;
// writer predicate li==16. ~10 VALU/value, chain ~50 cyc vs ~600+.
// fp32 sum reassociation only (~1e-7) — tolerance-safe.
//
// Carried:
//  - proj mfma_f32_16x16x32_f16 Markidis hi+lo split (3 MFMA/frag): ~22
//    mantissa bits, rel err ~1e-6 (bf16's 2^-8 failed in R2/R3). acc fp32.
//  - gate precompute: ~10 us (transcendentals off the scan chain).
//  - scan5 layout: 4 d-splits, 32-lane halves, depth-1 load rotation.
//  - out split-K=4 partials (dead-buffer aliased) + separate reduce: 15+3 us.

#define T_N   64
#define B_N   16
#define DIM_N 512
#define H_N   8
#define DH_N  64

#define OUT_ELEMS   524288   // T*B*DIM
#define KV_ELEMS    2097152  // B*H*FD*Dh
#define PROJ_ELEMS  2719744  // 5*524288 + 3*32768

typedef _Float16 f16;
typedef f16   f16x8 __attribute__((ext_vector_type(8)));
typedef float f32x4 __attribute__((ext_vector_type(4)));

__device__ __forceinline__ float sigmoidf_(float x) {
    return 1.0f / (1.0f + __expf(-x));
}

// ---------------------------------------------------------------------------
// DPP half-wave (32-lane) sum reduction, VALU-pipe only (no LDS).
// Stages: xor1 (quad_perm 0xB1), xor2 (quad_perm 0x4E), row_half_mirror
// (0x141), row_mirror (0x140), row_bcast15 (0x142, rows 1&3 only).
// Mirrors are xor-equivalent because all lanes of a combined group already
// hold the group sum. Result valid in lanes 16-31 (half 0) and 48-63
// (half 1), i.e. (l&31)==16..31; writer uses li==16.
// ---------------------------------------------------------------------------
template <int CTRL, int RM>
__device__ __forceinline__ float dpp_add_(float x) {
    int mv = __builtin_amdgcn_update_dpp(__float_as_int(x), __float_as_int(x),
                                         CTRL, RM, 0xF, false);
    return x + __int_as_float(mv);
}
__device__ __forceinline__ float half_reduce_dpp(float x) {
    x = dpp_add_<0xB1, 0xF>(x);   // quad_perm [1,0,3,2]  (xor 1)
    x = dpp_add_<0x4E, 0xF>(x);   // quad_perm [2,3,0,1]  (xor 2)
    x = dpp_add_<0x141, 0xF>(x);  // row_half_mirror      (xor 4 equiv)
    x = dpp_add_<0x140, 0xF>(x);  // row_mirror           (xor 8 equiv)
    x = dpp_add_<0x142, 0xA>(x);  // row_bcast15 -> rows 1,3 (xor 16 equiv)
    return x;
}

// ---------------------------------------------------------------------------
// gemm64_core (PROVEN, vector fp32): kept for out-GEMM.
// ---------------------------------------------------------------------------
__device__ __forceinline__ void gemm64_core(const float* __restrict__ A,
                                            const float* __restrict__ W,
                                            const float* __restrict__ bias,
                                            float* __restrict__ C, int N,
                                            int mb, int nb, int kBase, int kLen) {
    const int nbase = nb * 64;
    if (nbase >= N) return;

    __shared__ float As[2][16][68];
    __shared__ float Bs[2][16][68];

    const int tid = threadIdx.x;
    const int mbase = mb * 64;
    const int tx = tid & 15;
    const int ty = tid >> 4;
    const int sr = tid >> 2;
    const int sk = (tid & 3) << 2;
    const bool wok = (nbase + sr) < N;

    const float* Ap = A + (size_t)(mbase + sr) * 512 + kBase + sk;
    const float* Wp = W + (size_t)(nbase + sr) * 512 + kBase + sk;

    float4 av = *(const float4*)Ap;
    float4 wv = wok ? *(const float4*)Wp : make_float4(0.f, 0.f, 0.f, 0.f);
    As[0][sk + 0][sr] = av.x; As[0][sk + 1][sr] = av.y;
    As[0][sk + 2][sr] = av.z; As[0][sk + 3][sr] = av.w;
    Bs[0][sk + 0][sr] = wv.x; Bs[0][sk + 1][sr] = wv.y;
    Bs[0][sk + 2][sr] = wv.z; Bs[0][sk + 3][sr] = wv.w;

    float acc[4][4];
    #pragma unroll
    for (int i = 0; i < 4; ++i)
        #pragma unroll
        for (int j = 0; j < 4; ++j) acc[i][j] = 0.f;

    for (int k0 = 0; k0 < kLen; k0 += 16) {
        const int buf = (k0 >> 4) & 1;
        __syncthreads();
        const bool more = (k0 + 16) < kLen;
        if (more) {
            av = *(const float4*)(Ap + k0 + 16);
            wv = wok ? *(const float4*)(Wp + k0 + 16) : make_float4(0.f, 0.f, 0.f, 0.f);
        }
        #pragma unroll
        for (int k = 0; k < 16; ++k) {
            float4 a  = *(const float4*)&As[buf][k][ty << 2];
            float4 bq = *(const float4*)&Bs[buf][k][tx << 2];
            float ar[4] = {a.x, a.y, a.z, a.w};
            float br[4] = {bq.x, bq.y, bq.z, bq.w};
            #pragma unroll
            for (int i = 0; i < 4; ++i)
                #pragma unroll
                for (int j = 0; j < 4; ++j)
                    acc[i][j] = fmaf(ar[i], br[j], acc[i][j]);
        }
        if (more) {
            const int nbuf = buf ^ 1;
            As[nbuf][sk + 0][sr] = av.x; As[nbuf][sk + 1][sr] = av.y;
            As[nbuf][sk + 2][sr] = av.z; As[nbuf][sk + 3][sr] = av.w;
            Bs[nbuf][sk + 0][sr] = wv.x; Bs[nbuf][sk + 1][sr] = wv.y;
            Bs[nbuf][sk + 2][sr] = wv.z; Bs[nbuf][sk + 3][sr] = wv.w;
        }
    }

    #pragma unroll
    for (int i = 0; i < 4; ++i) {
        const int m = mbase + (ty << 2) + i;
        #pragma unroll
        for (int j = 0; j < 4; ++j) {
            const int n = nbase + (tx << 2) + j;
            if (n < N) {
                float v = acc[i][j];
                if (bias) v += bias[n];
                C[(size_t)m * N + n] = v;
            }
        }
    }
}

struct ProjW {
    const float* W[8];
    float*       D[8];
};

// ---------------------------------------------------------------------------
// proj_mfma_kernel (R19, PROVEN): 64x64 tile, 4 waves x 32x32 sub-tile via
// mfma_f32_16x16x32_f16 hi/lo split (3 MFMAs per fragment pair). Double-
// buffered LDS, stride 40 f16. Grid mapping z = id&7 -> XCD swizzle.
// ---------------------------------------------------------------------------
__device__ __forceinline__ void cvt_split_store(f16* __restrict__ dh,
                                                f16* __restrict__ dl,
                                                float4 v0, float4 v1) {
    float x[8] = {v0.x, v0.y, v0.z, v0.w, v1.x, v1.y, v1.z, v1.w};
    f16x8 h, lo;
    #pragma unroll
    for (int e = 0; e < 8; ++e) {
        f16 hh = (f16)x[e];
        h[e]  = hh;
        lo[e] = (f16)(x[e] - (float)hh);
    }
    *(f16x8*)dh = h;
    *(f16x8*)dl = lo;
}

__global__ __launch_bounds__(256) void proj_mfma_kernel(const float* __restrict__ X,
                                                        ProjW a) {
    const int id = blockIdx.x;
    const int z = id & 7;
    const int rem = id >> 3;
    const int mb = rem & 15;
    const int nb = rem >> 4;
    const int N = (z < 5) ? 512 : 32;
    const int nbase = nb * 64;
    if (nbase >= N) return;

    const float* __restrict__ W = a.W[z];
    float* __restrict__ C = a.D[z];
    const int mbase = mb * 64;

    __shared__ f16 AsH[2][64][40];
    __shared__ f16 AsL[2][64][40];
    __shared__ f16 BsH[2][64][40];
    __shared__ f16 BsL[2][64][40];

    const int tid = threadIdx.x;
    const int sr = tid >> 2;
    const int kq = (tid & 3) << 3;
    const bool wok = (nbase + sr) < N;
    const float* Ap = X + (size_t)(mbase + sr) * 512 + kq;
    const float* Wp = W + (size_t)(nbase + sr) * 512 + kq;

    const int l  = tid & 63;
    const int w  = tid >> 6;
    const int wr = (w >> 1) << 5;
    const int wc = (w & 1) << 5;
    const int lr = l & 15;
    const int lk = (l >> 4) << 3;

    f32x4 acc[2][2] = {};

    float4 xa0 = *(const float4*)(Ap);
    float4 xa1 = *(const float4*)(Ap + 4);
    float4 wb0 = wok ? *(const float4*)(Wp)     : make_float4(0.f, 0.f, 0.f, 0.f);
    float4 wb1 = wok ? *(const float4*)(Wp + 4) : make_float4(0.f, 0.f, 0.f, 0.f);
    cvt_split_store(&AsH[0][sr][kq], &AsL[0][sr][kq], xa0, xa1);
    cvt_split_store(&BsH[0][sr][kq], &BsL[0][sr][kq], wb0, wb1);

    for (int k0 = 0; k0 < 512; k0 += 32) {
        const int buf = (k0 >> 5) & 1;
        __syncthreads();
        const bool more = (k0 + 32) < 512;
        if (more) {
            xa0 = *(const float4*)(Ap + k0 + 32);
            xa1 = *(const float4*)(Ap + k0 + 36);
            wb0 = wok ? *(const float4*)(Wp + k0 + 32) : make_float4(0.f, 0.f, 0.f, 0.f);
            wb1 = wok ? *(const float4*)(Wp + k0 + 36) : make_float4(0.f, 0.f, 0.f, 0.f);
        }

        f16x8 aH[2], aL[2], bH[2], bL[2];
        #pragma unroll
        for (int i = 0; i < 2; ++i) {
            const int row = wr + i * 16 + lr;
            aH[i] = *(const f16x8*)&AsH[buf][row][lk];
            aL[i] = *(const f16x8*)&AsL[buf][row][lk];
        }
        #pragma unroll
        for (int j = 0; j < 2; ++j) {
            const int col = wc + j * 16 + lr;
            bH[j] = *(const f16x8*)&BsH[buf][col][lk];
            bL[j] = *(const f16x8*)&BsL[buf][col][lk];
        }

        #pragma unroll
        for (int i = 0; i < 2; ++i)
            #pragma unroll
            for (int j = 0; j < 2; ++j) {
                acc[i][j] = __builtin_amdgcn_mfma_f32_16x16x32_f16(aH[i], bH[j], acc[i][j], 0, 0, 0);
                acc[i][j] = __builtin_amdgcn_mfma_f32_16x16x32_f16(aH[i], bL[j], acc[i][j], 0, 0, 0);
                acc[i][j] = __builtin_amdgcn_mfma_f32_16x16x32_f16(aL[i], bH[j], acc[i][j], 0, 0, 0);
            }

        if (more) {
            const int nbuf = buf ^ 1;
            cvt_split_store(&AsH[nbuf][sr][kq], &AsL[nbuf][sr][kq], xa0, xa1);
            cvt_split_store(&BsH[nbuf][sr][kq], &BsL[nbuf][sr][kq], wb0, wb1);
        }
    }

    // C/D layout (m89/m91): col = lane&15, row = (lane>>4)*4 + reg
    #pragma unroll
    for (int j = 0; j < 2; ++j) {
        const int n = nbase + wc + j * 16 + lr;
        if (n < N) {
            #pragma unroll
            for (int i = 0; i < 2; ++i) {
                #pragma unroll
                for (int q = 0; q < 4; ++q) {
                    const int m = mbase + wr + i * 16 + ((l >> 4) << 2) + q;
                    C[(size_t)m * N + n] = acc[i][j][q];
                }
            }
        }
    }
}

// Fallback out GEMM (full K) — tiny-ws path only.
__global__ __launch_bounds__(256) void out_gemm_kernel(const float* __restrict__ A,
                                                       const float* __restrict__ W,
                                                       const float* __restrict__ bias,
                                                       float* __restrict__ C) {
    gemm64_core(A, W, bias, C, 512, blockIdx.x, blockIdx.y, 0, 512);
}

// out GEMM split-K=4 partials: grid 512, id = m + 16*(n + 8*kq); XCD = m%8.
struct OutP { float* P[4]; };
__global__ __launch_bounds__(256) void out_partial_kernel(const float* __restrict__ A,
                                                          const float* __restrict__ W,
                                                          OutP p) {
    const int id = blockIdx.x;
    const int m = id & 15;
    const int n = (id >> 4) & 7;
    const int kq = id >> 7;
    gemm64_core(A, W, nullptr, p.P[kq], 512, m, n, kq * 128, 128);
}

// reduce: out = P0+P1+P2+P3 + bias (fixed order -> deterministic). 131072 f4.
__global__ __launch_bounds__(256) void out_reduce_kernel(
    const float* __restrict__ p0, const float* __restrict__ p1,
    const float* __restrict__ p2, const float* __restrict__ p3,
    const float* __restrict__ bias, float* __restrict__ out) {
    const int i = blockIdx.x * 256 + threadIdx.x;     // float4 index
    float4 a = ((const float4*)p0)[i];
    float4 b = ((const float4*)p1)[i];
    float4 c = ((const float4*)p2)[i];
    float4 d = ((const float4*)p3)[i];
    float4 bv = ((const float4*)bias)[i & 127];
    float4 r;
    r.x = a.x + b.x + c.x + d.x + bv.x;
    r.y = a.y + b.y + c.y + d.y + bv.y;
    r.z = a.z + b.z + c.z + d.z + bv.z;
    r.w = a.w + b.w + c.w + d.w + bv.w;
    ((float4*)out)[i] = r;
}

// ---------------------------------------------------------------------------
// gate_kernel: precompute disc/gk/phiq per (t,b,h,D) and gv per (t,b,h,d).
// grid (8 h, 1024 rows) -> wg id % 8 = h (writer XCD = scan reader XCD).
// ---------------------------------------------------------------------------
__global__ __launch_bounds__(256) void gate_kernel(
    const float* __restrict__ qb,  const float* __restrict__ kb,
    const float* __restrict__ vb,  const float* __restrict__ bb,
    const float* __restrict__ gb,  const float* __restrict__ p1b,
    const float* __restrict__ p2b, const float* __restrict__ p3b,
    const int* __restrict__ term,
    float* __restrict__ disc_g, float* __restrict__ gk_g,
    float* __restrict__ phiq_g, float* __restrict__ gv_g) {
    const int h = blockIdx.x;
    const int row = blockIdx.y;        // t*16 + b
    const int D = threadIdx.x;
    const int e = D >> 6, di = D & 63;
    const size_t base = (size_t)row * 512 + h * 64;
    const size_t pb = (size_t)row * 32 + h * 4;

    float q = qb[base + di], k = kb[base + di], g = gb[base + di];
    float p1 = p1b[pb + e], p2 = p2b[pb + e], p3 = p3b[pb + e];
    float mask = 1.0f - (float)term[row];
    float gf = sigmoidf_(p3) * sigmoidf_(g);

    const size_t o = ((size_t)row * 8 + h) * 256 + D;
    disc_g[o] = (1.0f - gf) * mask;
    gk_g[o]   = fmaxf(p1, 0.f) * k * gf;
    phiq_g[o] = fmaxf(p2, 0.f) * q;
    if (D < 64)
        gv_g[((size_t)row * 8 + h) * 64 + D] = vb[base + D] * sigmoidf_(bb[base + D]);
}

// ---------------------------------------------------------------------------
// scan8 (R22): scan5 structure + DPP reduce. Grid 512: blk = s*128 + bh
// (XCD = bh%8 = h). Block 256 thr = 4 waves; wave = 2 INDEPENDENT 32-lane
// halves. Half (l>>5) owns cols s*16+w*4+2*half+{0,1}. Lane li = l&31 owns
// D = 8*li..8*li+8. Depth-1 load rotation (proven); per-step reduction on
// the VALU pipe via half_reduce_dpp; sums valid at li==16 (both halves).
// attn overwrites vb (scan never reads vb; out_partial reads it after).
// ---------------------------------------------------------------------------
__global__ __launch_bounds__(256) void scan8_kernel(
    const float* __restrict__ disc_g, const float* __restrict__ gk_g,
    const float* __restrict__ phiq_g, const float* __restrict__ gv_g,
    float* __restrict__ vb /* attn out */,
    const float* __restrict__ kv0, const float* __restrict__ nm0,
    float* __restrict__ dout) {
    const int blk = blockIdx.x;       // 512 = 4 splits x 128 bh
    const int bh = blk & 127;
    const int s  = blk >> 7;          // 0..3
    const int b  = bh >> 3;
    const int h  = bh & 7;
    const int tid = threadIdx.x;
    const int w = tid >> 6;
    const int l = tid & 63;
    const int half = l >> 5;
    const int li = l & 31;
    const int d0 = s * 16 + w * 4 + half * 2;   // lane's 2 d-cols
    const int D0 = li << 3;                     // lane's 8 D

    float kv[8][2];
    float nm[8];
    {
        const float* kp = kv0 + ((size_t)bh * 256 + D0) * 64 + d0;
        #pragma unroll
        for (int j = 0; j < 8; ++j) {
            float2 r = *(const float2*)(kp + (size_t)j * 64);
            kv[j][0] = r.x; kv[j][1] = r.y;
        }
        float4 na  = *(const float4*)(nm0 + (size_t)bh * 256 + D0);
        float4 nb_ = *(const float4*)(nm0 + (size_t)bh * 256 + D0 + 4);
        nm[0] = na.x; nm[1] = na.y; nm[2] = na.z; nm[3] = na.w;
        nm[4] = nb_.x; nm[5] = nb_.y; nm[6] = nb_.z; nm[7] = nb_.w;
    }

    float4 cd0, cd1, cg0, cg1, cp0, cp1; float2 cgv;
    {
        const size_t go = ((size_t)b * 8 + h) * 256 + D0;
        cd0 = *(const float4*)(disc_g + go);  cd1 = *(const float4*)(disc_g + go + 4);
        cg0 = *(const float4*)(gk_g + go);    cg1 = *(const float4*)(gk_g + go + 4);
        cp0 = *(const float4*)(phiq_g + go);  cp1 = *(const float4*)(phiq_g + go + 4);
        cgv = *(const float2*)(gv_g + ((size_t)b * 8 + h) * 64 + d0);
    }

    for (int t = 0; t < T_N; ++t) {
        const int row = t * B_N + b;
        const size_t base = (size_t)row * 512 + h * 64;

        float4 nd0 = {}, nd1 = {}, ng0 = {}, ng1 = {}, np0 = {}, np1 = {};
        float2 ngv = {};
        if (t + 1 < T_N) {
            const size_t go2 = ((size_t)(row + B_N) * 8 + h) * 256 + D0;
            nd0 = *(const float4*)(disc_g + go2); nd1 = *(const float4*)(disc_g + go2 + 4);
            ng0 = *(const float4*)(gk_g + go2);   ng1 = *(const float4*)(gk_g + go2 + 4);
            np0 = *(const float4*)(phiq_g + go2); np1 = *(const float4*)(phiq_g + go2 + 4);
            ngv = *(const float2*)(gv_g + ((size_t)(row + B_N) * 8 + h) * 64 + d0);
        }

        const float dj[8]  = {cd0.x, cd0.y, cd0.z, cd0.w, cd1.x, cd1.y, cd1.z, cd1.w};
        const float gkj[8] = {cg0.x, cg0.y, cg0.z, cg0.w, cg1.x, cg1.y, cg1.z, cg1.w};
        const float phj[8] = {cp0.x, cp0.y, cp0.z, cp0.w, cp1.x, cp1.y, cp1.z, cp1.w};

        float den = 0.f, n0 = 0.f, n1 = 0.f;
        #pragma unroll
        for (int j = 0; j < 8; ++j) {
            nm[j] = dj[j] * nm[j] + gkj[j];
            den = fmaf(phj[j], nm[j], den);
            kv[j][0] = dj[j] * kv[j][0] + gkj[j] * cgv.x; n0 = fmaf(phj[j], kv[j][0], n0);
            kv[j][1] = dj[j] * kv[j][1] + gkj[j] * cgv.y; n1 = fmaf(phj[j], kv[j][1], n1);
        }

        n0  = half_reduce_dpp(n0);
        n1  = half_reduce_dpp(n1);
        den = half_reduce_dpp(den);

        if (li == 16) {
            vb[base + d0]     = n0 / (den + 1e-6f);
            vb[base + d0 + 1] = n1 / (den + 1e-6f);
        }

        cd0 = nd0; cd1 = nd1; cg0 = ng0; cg1 = ng1; cp0 = np0; cp1 = np1; cgv = ngv;
    }

    {
        float* kp = dout + OUT_ELEMS + ((size_t)bh * 256 + D0) * 64 + d0;
        #pragma unroll
        for (int j = 0; j < 8; ++j)
            *(float2*)(kp + (size_t)j * 64) = make_float2(kv[j][0], kv[j][1]);
        if (s == 0 && w == 0 && half == 0) {
            float* np = dout + OUT_ELEMS + KV_ELEMS + (size_t)bh * 256 + D0;
            *(float4*)np       = make_float4(nm[0], nm[1], nm[2], nm[3]);
            *(float4*)(np + 4) = make_float4(nm[4], nm[5], nm[6], nm[7]);
        }
    }
}

// ---------------------------------------------------------------------------
extern "C" void kernel_launch(void* const* d_in, const int* in_sizes, int n_in,
                              void* d_out, int out_size, void* d_ws, size_t ws_size,
                              hipStream_t stream) {
    (void)in_sizes; (void)n_in; (void)out_size;

    const float* X    = (const float*)d_in[0];
    const int*   term = (const int*)  d_in[1];
    const float* kv0  = (const float*)d_in[2];
    const float* nm0  = (const float*)d_in[3];
    const float* Wo   = (const float*)d_in[12];
    const float* bo   = (const float*)d_in[13];

    float* out = (float*)d_out;

    // ---- workspace (38.1 MB total — PROVEN available since R9) ----
    float* qb  = (float*)d_ws;            // proj outputs; qb/kb/bb/gb reused
    float* kb  = qb  + 524288;            // as out-GEMM partials after gate
    float* vb  = kb  + 524288;            // v, later attn
    float* bb  = vb  + 524288;
    float* gb  = bb  + 524288;
    float* p1b = gb  + 524288;
    float* p2b = p1b + 32768;
    float* p3b = p2b + 32768;
    float* disc_g = p3b + 32768;          // 26 MB gating region
    float* gk_g   = disc_g + 2097152;
    float* phiq_g = gk_g   + 2097152;
    float* gv_g   = phiq_g + 2097152;
    const size_t need_bytes = (size_t)(PROJ_ELEMS + 6815744) * 4;  // 38.1 MB
    const bool big = ws_size >= need_bytes;

    ProjW pa;
    pa.W[0] = (const float*)d_in[4];  pa.W[1] = (const float*)d_in[5];
    pa.W[2] = (const float*)d_in[6];  pa.W[3] = (const float*)d_in[7];
    pa.W[4] = (const float*)d_in[8];  pa.W[5] = (const float*)d_in[9];
    pa.W[6] = (const float*)d_in[10]; pa.W[7] = (const float*)d_in[11];
    pa.D[0] = qb;  pa.D[1] = kb;  pa.D[2] = vb;  pa.D[3] = bb;
    pa.D[4] = gb;  pa.D[5] = p1b; pa.D[6] = p2b; pa.D[7] = p3b;
    proj_mfma_kernel<<<1024, 256, 0, stream>>>(X, pa);

    gate_kernel<<<dim3(8, 1024), 256, 0, stream>>>(qb, kb, vb, bb, gb,
                                                   p1b, p2b, p3b, term,
                                                   disc_g, gk_g, phiq_g, gv_g);
    scan8_kernel<<<512, 256, 0, stream>>>(disc_g, gk_g, phiq_g, gv_g,
                                          vb, kv0, nm0, out);
    if (big) {
        // out = attn @ Wo^T + bo, split-K=4 into the dead q/k/b/g buffers
        OutP op; op.P[0] = qb; op.P[1] = kb; op.P[2] = bb; op.P[3] = gb;
        out_partial_kernel<<<512, 256, 0, stream>>>(vb, Wo, op);
        out_reduce_kernel<<<512, 256, 0, stream>>>(qb, kb, bb, gb, bo, out);
    } else {
        out_gemm_kernel<<<dim3(16, 8), 256, 0, stream>>>(vb, Wo, bo, out);
    }
}